// Round 8
// baseline (529.512 us; speedup 1.0000x reference)
//
#include <hip/hip_runtime.h>

// SE-block on MI355X, 5-dispatch pipeline.
// A: pool+sigmoid (2048 grid-stride blks) + sn1 Wt*u partials (272 blks) + scal zero
// B: gemm1 split-K partials (512 blks) + sn1r reduce->t1,||t1||^2 (34 blks)
// C: sn2 ||Wv||^2 -> scal[2],scal[3] (1024 blks)
// DE: per-sample hred + gemm2(w2 LDS tiles) + sigmoid + exact top-102 -> wgt (32 blks)
// F: out = x * wgt (2048 grid-stride blks)

#define KTOP 102

__device__ __forceinline__ float block_sum256(float v) {
  __shared__ float red[4];
  #pragma unroll
  for (int off = 32; off; off >>= 1) v += __shfl_down(v, off, 64);
  int lane = threadIdx.x & 63;
  int w = threadIdx.x >> 6;
  if (lane == 0) red[w] = v;
  __syncthreads();
  float r = 0.f;
  if (threadIdx.x == 0) r = red[0] + red[1] + red[2] + red[3];
  return r;  // valid on thread 0 only
}

// A: blocks [0,2048) pool grid-stride over 16384 planes; [2048,2304) sn1-w1; [2304,2320) sn1-w2.
__global__ __launch_bounds__(256) void k_a(const float* __restrict__ x, const float* __restrict__ w1,
                                           const float* __restrict__ w2, const float* __restrict__ u1,
                                           const float* __restrict__ u2, float* __restrict__ p,
                                           float* __restrict__ part1, float* __restrict__ part1b,
                                           float* __restrict__ scal) {
  __shared__ float sx[3136];
  __shared__ float su[64];
  int b = blockIdx.x, t = threadIdx.x;
  if (b < 2048) {
    for (int plane = b; plane < 16384; plane += 2048) {
      __syncthreads();   // protect sx reuse across iterations
      const float4* xp4 = (const float4*)(x + (size_t)plane * 3136);
      float4* sx4 = (float4*)sx;
      for (int e = t; e < 784; e += 256) sx4[e] = xp4[e];
      __syncthreads();
      int w = t >> 4, lane = t & 15;
      int wr = w >> 2, wc = w & 3;
      float acc = 0.f;
      for (int e = lane; e < 196; e += 16) {
        int r = e / 14, cc = e - r * 14;
        acc += sx[(14 * wr + r) * 56 + 14 * wc + cc];
      }
      #pragma unroll
      for (int off = 8; off; off >>= 1) acc += __shfl_down(acc, off, 16);
      if (lane == 0) {
        float m = acc * (1.f / 196.f);
        p[(size_t)plane * 16 + w] = 1.f / (1.f + expf(-m));
      }
    }
  } else if (b < 2304) {
    int bb = b - 2048;
    if (bb == 0 && t < 4) scal[t] = 0.f;   // zero accumulators for B/C
    int jb = bb & 31, ic = bb >> 5;
    if (t < 64) su[t] = u1[ic * 64 + t];
    __syncthreads();
    int j = jb * 256 + t;
    const float* base = w1 + (size_t)(ic * 64) * 8192 + j;
    float acc = 0.f;
    #pragma unroll 4
    for (int i = 0; i < 64; ++i) acc += base[(size_t)i * 8192] * su[i];
    part1[ic * 8192 + j] = acc;
  } else {
    int bb = b - 2304;
    int jb = bb & 1, ic = bb >> 1;
    if (t < 64) su[t] = u2[ic * 64 + t];
    __syncthreads();
    int j = jb * 256 + t;
    const float* base = w2 + (size_t)(ic * 64) * 512 + j;
    float acc = 0.f;
    #pragma unroll 4
    for (int i = 0; i < 64; ++i) acc += base[(size_t)i * 512] * su[i];
    part1b[ic * 512 + j] = acc;
  }
}

// B: blocks [0,512) gemm1 (o-tile = b&7, k-split = b>>3); [512,544) sn1r-w1; [544,546) sn1r-w2.
__global__ __launch_bounds__(256) void k_b(const float* __restrict__ p, const float* __restrict__ w1,
                                           const float* __restrict__ part1, const float* __restrict__ part1b,
                                           float* __restrict__ part, float* __restrict__ t1,
                                           float* __restrict__ t1b, float* __restrict__ scal) {
  __shared__ float sp[32][132];
  __shared__ float sw[64][132];
  int b = blockIdx.x, t = threadIdx.x;
  if (b < 512) {
    int o0 = (b & 7) * 64;
    int k0 = (b >> 3) * 128;
    for (int idx = t; idx < 1024; idx += 256) {          // 32 rows x 32 float4
      int r = idx >> 5, c4 = (idx & 31) << 2;
      *(float4*)&sp[r][c4] = *(const float4*)&p[(size_t)r * 8192 + k0 + c4];
    }
    for (int idx = t; idx < 2048; idx += 256) {          // 64 rows x 32 float4
      int r = idx >> 5, c4 = (idx & 31) << 2;
      *(float4*)&sw[r][c4] = *(const float4*)&w1[(size_t)(o0 + r) * 8192 + k0 + c4];
    }
    __syncthreads();
    int m = t & 31, g = t >> 5;
    int n0 = g * 4;
    float acc[4][2] = {{0.f, 0.f}, {0.f, 0.f}, {0.f, 0.f}, {0.f, 0.f}};
    for (int kk = 0; kk < 128; kk += 4) {
      float4 wa = *(const float4*)&sw[m][kk];
      float4 wb = *(const float4*)&sw[m + 32][kk];
      #pragma unroll
      for (int ni = 0; ni < 4; ++ni) {
        float4 pv = *(const float4*)&sp[n0 + ni][kk];
        acc[ni][0] += pv.x * wa.x + pv.y * wa.y + pv.z * wa.z + pv.w * wa.w;
        acc[ni][1] += pv.x * wb.x + pv.y * wb.y + pv.z * wb.z + pv.w * wb.w;
      }
    }
    size_t base = (size_t)(b >> 3) * 16384;
    #pragma unroll
    for (int ni = 0; ni < 4; ++ni) {
      part[base + (n0 + ni) * 512 + o0 + m] = acc[ni][0];
      part[base + (n0 + ni) * 512 + o0 + m + 32] = acc[ni][1];
    }
  } else if (b < 544) {
    int j = (b - 512) * 256 + t;
    float s = 0.f;
    #pragma unroll
    for (int ic = 0; ic < 8; ++ic) s += part1[ic * 8192 + j];
    t1[j] = s;
    float tot = block_sum256(s * s);
    if (t == 0) atomicAdd(&scal[0], tot);
  } else {
    int j = (b - 544) * 256 + t;
    float s = 0.f;
    #pragma unroll
    for (int ic = 0; ic < 8; ++ic) s += part1b[ic * 512 + j];
    t1b[j] = s;
    float tot = block_sum256(s * s);
    if (t == 0) atomicAdd(&scal[1], tot);
  }
}

// C: blocks [0,512) sn2-w1; [512,1024) sn2-w2. Accumulate ||Wv||^2.
__global__ __launch_bounds__(256) void k_c(const float* __restrict__ w1, const float* __restrict__ w2,
                                           const float* __restrict__ t1, const float* __restrict__ t1b,
                                           float* __restrict__ scal) {
  int b = blockIdx.x, t = threadIdx.x;
  if (b < 512) {
    float inv = 1.f / (sqrtf(scal[0]) + 1e-12f);
    const float4* row = (const float4*)(w1 + (size_t)b * 8192);
    const float4* tv = (const float4*)t1;
    float acc = 0.f;
    for (int q = t; q < 2048; q += 256) {
      float4 a = row[q], v = tv[q];
      acc += a.x * v.x + a.y * v.y + a.z * v.z + a.w * v.w;
    }
    float tot = block_sum256(acc);
    if (t == 0) { float r = tot * inv; atomicAdd(&scal[2], r * r); }
  } else {
    int i = b - 512;
    float inv = 1.f / (sqrtf(scal[1]) + 1e-12f);
    const float4* row = (const float4*)(w2 + (size_t)i * 512);
    const float4* tv = (const float4*)t1b;
    float acc = 0.f;
    if (t < 128) {
      float4 a = row[t], v = tv[t];
      acc = a.x * v.x + a.y * v.y + a.z * v.z + a.w * v.w;
    }
    float tot = block_sum256(acc);
    if (t == 0) { float r = tot * inv; atomicAdd(&scal[3], r * r); }
  }
}

// DE: one block per sample n. hred (k-split reduce + relu) -> h in LDS;
// gemm2 via w2 LDS tiles (64 rows x 512, pad stride 516);
// sigmoid; exact top-102 radix select; write wgt row.
__global__ __launch_bounds__(256) void k_de(const float* __restrict__ part, const float* __restrict__ w2,
                                            const float* __restrict__ scal, float* __restrict__ wgt) {
  __shared__ float tile[64][516];   // 132KB
  __shared__ float sh[512];
  __shared__ float ss[512];
  __shared__ unsigned sb[512];
  __shared__ int cnt;
  int n = blockIdx.x, t = threadIdx.x;
  // 1) h row for this n: reduce 64 k-splits, relu (sigma deferred into sigmoid arg)
  {
    float a0 = 0.f, a1 = 0.f;
    for (int ks = 0; ks < 64; ++ks) {
      const float* pr = part + (size_t)ks * 16384 + (size_t)n * 512;
      a0 += pr[t];
      a1 += pr[t + 256];
    }
    sh[t] = fmaxf(a0, 0.f);
    sh[t + 256] = fmaxf(a1, 0.f);
  }
  __syncthreads();
  // 2) cache this thread's h k-segment in registers (reused across all 8 tiles)
  int g = t >> 2, r = t & 3;          // g: o-row in tile, r: k-quarter
  float4 hreg[32];
  #pragma unroll
  for (int i = 0; i < 32; ++i) hreg[i] = *(const float4*)&sh[r * 128 + i * 4];
  float A2 = scal[2], B2 = scal[3];
  float sig1 = A2 / (sqrtf(A2) + 1e-12f);
  float sig2 = B2 / (sqrtf(B2) + 1e-12f);
  float inv = 1.f / (sig1 * sig2);
  for (int ti = 0; ti < 8; ++ti) {
    int o0 = ti * 64;
    __syncthreads();   // protect tile reuse
    for (int idx = t; idx < 8192; idx += 256) {        // 64 rows x 128 float4
      int row = idx >> 7, c4 = (idx & 127) << 2;
      *(float4*)&tile[row][c4] = *(const float4*)&w2[(size_t)(o0 + row) * 512 + c4];
    }
    __syncthreads();
    float d = 0.f;
    #pragma unroll
    for (int i = 0; i < 32; ++i) {
      float4 wv = *(const float4*)&tile[g][r * 128 + i * 4];
      float4 hv = hreg[i];
      d += wv.x * hv.x + wv.y * hv.y + wv.z * hv.z + wv.w * hv.w;
    }
    d += __shfl_xor(d, 1, 64);
    d += __shfl_xor(d, 2, 64);
    if (r == 0) {
      float sv = 1.f / (1.f + expf(-d * inv));
      ss[o0 + g] = sv;
      sb[o0 + g] = __float_as_uint(sv);
    }
  }
  __syncthreads();
  // 3) exact top-102: radix select on positive floats (uint order == float order)
  int rr = KTOP;
  unsigned prefix = 0u;
  for (int bit = 31; bit >= 0; --bit) {
    if (t == 0) cnt = 0;
    __syncthreads();
    unsigned hi = prefix | (1u << bit);
    unsigned mhi = ~((1u << bit) - 1u);
    unsigned long long c0 = __ballot((sb[t] & mhi) == hi);
    unsigned long long c1 = __ballot((sb[t + 256] & mhi) == hi);
    if ((t & 63) == 0) atomicAdd(&cnt, __popcll(c0) + __popcll(c1));
    __syncthreads();
    int c = cnt;
    __syncthreads();
    if (c >= rr) prefix = hi; else rr -= c;
  }
  if (t == 0) cnt = 0;
  __syncthreads();
  {
    unsigned long long g0 = __ballot(sb[t] > prefix);
    unsigned long long g1 = __ballot(sb[t + 256] > prefix);
    if ((t & 63) == 0) atomicAdd(&cnt, __popcll(g0) + __popcll(g1));
  }
  __syncthreads();
  int alloweq = KTOP - cnt;   // ties: keep lowest indices first (jax top_k order)
  for (int e = t; e < 512; e += 256) {
    unsigned v = sb[e];
    bool keep = v > prefix;
    if (!keep && v == prefix) {
      int rank = 0;
      for (int j = 0; j < e; ++j) rank += (sb[j] == prefix);
      keep = rank < alloweq;
    }
    wgt[(size_t)n * 512 + e] = keep ? ss[e] : 0.f;
  }
}

// F: out = x * wgt[n,c], 2048 blocks grid-stride over 16384 planes.
__global__ __launch_bounds__(256) void k_scale(const float* __restrict__ x, const float* __restrict__ wgt,
                                               float* __restrict__ out) {
  for (int plane = blockIdx.x; plane < 16384; plane += 2048) {
    float g = wgt[plane];
    const float4* xi = (const float4*)(x + (size_t)plane * 3136);
    float4* oo = (float4*)(out + (size_t)plane * 3136);
    for (int e = threadIdx.x; e < 784; e += 256) {
      float4 v = xi[e];
      v.x *= g; v.y *= g; v.z *= g; v.w *= g;
      oo[e] = v;
    }
  }
}

extern "C" void kernel_launch(void* const* d_in, const int* in_sizes, int n_in,
                              void* d_out, int out_size, void* d_ws, size_t ws_size,
                              hipStream_t stream) {
  const float* x  = (const float*)d_in[0];
  const float* w1 = (const float*)d_in[1];
  const float* w2 = (const float*)d_in[2];
  const float* u1 = (const float*)d_in[3];
  const float* u2 = (const float*)d_in[4];
  float* out = (float*)d_out;
  float* ws = (float*)d_ws;

  // ws layout (floats), all float4-aligned
  float* scal   = ws + 0;        // 4: ||t1||^2, ||t1b||^2, ||t2||^2, ||t2b||^2
  float* t1     = ws + 4;        // 8192
  float* t1b    = ws + 8196;     // 512
  float* p      = ws + 8708;     // 32*8192
  float* part1  = ws + 270852;   // 8*8192
  float* part1b = ws + 336388;   // 8*512
  float* part   = ws + 340484;   // 64*16384
  float* wgt    = ws + 1389060;  // 16384

  k_a<<<2320, 256, 0, stream>>>(x, w1, w2, u1, u2, p, part1, part1b, scal);
  k_b<<<546, 256, 0, stream>>>(p, w1, part1, part1b, part, t1, t1b, scal);
  k_c<<<1024, 256, 0, stream>>>(w1, w2, t1, t1b, scal);
  k_de<<<32, 256, 0, stream>>>(part, w2, scal, wgt);
  k_scale<<<2048, 256, 0, stream>>>(x, wgt, out);
}